// Round 10
// baseline (313.539 us; speedup 1.0000x reference)
//
#include <hip/hip_runtime.h>

#define N_NODES 50000
#define N_EDGES 1600000
#define DIM 64
#define NBK 196          // buckets of 256 dst-nodes
#define BIN_BLOCKS 391   // ceil(1.6M / 4096)
#define CSR_CAP 12288    // per-bucket slots (mean 8192 + pad + margin)
#define QCAP 3072        // per-quarter slots (mean ~2270 padded, ~9-sigma margin)
#define PLANE ((size_t)(N_NODES + 1) * 32)   // one feature-half plane, bf16 elems

typedef unsigned uv4 __attribute__((ext_vector_type(4)));  // nontemporal-compatible

// f32 -> bf16 round-to-nearest-even
__device__ __forceinline__ unsigned short f2bf(float f) {
    union { float f; unsigned u; } v; v.f = f;
    unsigned r = v.u + 0x7FFF + ((v.u >> 16) & 1);
    return (unsigned short)(r >> 16);
}
__device__ __forceinline__ float bf_lo(unsigned u) {
    union { unsigned u; float f; } v; v.u = u << 16;  return v.f;
}
__device__ __forceinline__ float bf_hi(unsigned u) {
    union { unsigned u; float f; } v; v.u = u & 0xFFFF0000u;  return v.f;
}

// cursors: 1 per 64B line
__global__ __launch_bounds__(256) void init_bcur(int* __restrict__ bcur) {
    if (threadIdx.x < NBK) bcur[threadIdx.x * 16] = threadIdx.x * CSR_CAP;
}

// Partition edges into per-bucket padded regions via LDS staging. (R6-proven)
// packed word: ((dst & 255) << 16) | src   (src < 50000 < 2^16)
__global__ __launch_bounds__(256) void bin_edges(const int* __restrict__ src,
                                                 const int* __restrict__ dst,
                                                 int* __restrict__ bcur,
                                                 int* __restrict__ binned) {
    __shared__ int cnt[NBK];
    __shared__ int lofs[NBK];
    __shared__ int shiftv[NBK];
    __shared__ int sb[256];
    __shared__ int stag[4096];
    __shared__ unsigned char stb[4096];
    int tid = threadIdx.x;
    if (tid < NBK) cnt[tid] = 0;
    __syncthreads();

    int base = blockIdx.x * 4096;
    int nedge = N_EDGES - base;
    if (nedge > 4096) nedge = 4096;

    int myb[16], myr[16], myp[16];
#pragma unroll
    for (int i = 0; i < 16; ++i) {
        int e = base + i * 256 + tid;
        myb[i] = -1;
        if (e < N_EDGES) {
            int s = src[e], d = dst[e];
            int b = d >> 8;
            myb[i] = b;
            myp[i] = ((d & 255) << 16) | s;
            myr[i] = atomicAdd(&cnt[b], 1);
        }
    }
    __syncthreads();

    int c = (tid < NBK) ? cnt[tid] : 0;
    sb[tid] = c;
    __syncthreads();
    for (int off = 1; off < 256; off <<= 1) {
        int u = (tid >= off) ? sb[tid - off] : 0;
        __syncthreads();
        sb[tid] += u;
        __syncthreads();
    }
    if (tid < NBK) {
        lofs[tid] = sb[tid] - c;
        if (c) shiftv[tid] = atomicAdd(&bcur[tid * 16], c) - lofs[tid];
    }
    __syncthreads();

#pragma unroll
    for (int i = 0; i < 16; ++i) {
        if (myb[i] >= 0) {
            int idx = lofs[myb[i]] + myr[i];
            stag[idx] = myp[i];
            stb[idx] = (unsigned char)myb[i];
        }
    }
    __syncthreads();

    for (int i = tid; i < nedge; i += 256)
        binned[i + shiftv[stb[i]]] = stag[i];
}

// One workgroup per (bucket, dst-quarter). Counts padded to mult-8 with dummy
// src = N_NODES (zero row). nodeinfo = (padded_cnt << 23) | pos, pos%8==0.
__global__ __launch_bounds__(256) void build_csr(const int* __restrict__ binned,
                                                 const int* __restrict__ bcur,
                                                 unsigned* __restrict__ nodeinfo,
                                                 unsigned short* __restrict__ csr16) {
    __shared__ int cnt[64], cnt2[64], ofs[64], sb[64];
    __shared__ int qtot;
    int tid = threadIdx.x;
    int b = blockIdx.x >> 2;
    int q = blockIdx.x & 3;
    int ibase = b * CSR_CAP;
    int qbase = (b * 4 + q) * QCAP;
    int m = bcur[b * 16] - ibase;
    if (m > CSR_CAP) m = CSR_CAP;
    if (tid < 64) { cnt[tid] = 0; cnt2[tid] = 0; }
    __syncthreads();

    for (int i = tid; i < m; i += 256) {
        int dl = (binned[ibase + i] >> 16) & 255;
        if ((dl >> 6) == q) atomicAdd(&cnt[dl & 63], 1);
    }
    __syncthreads();

    int v = 0;
    if (tid < 64) { v = (cnt[tid] + 7) & ~7; sb[tid] = v; }
    __syncthreads();
    for (int off = 1; off < 64; off <<= 1) {
        int u = (tid >= off && tid < 64) ? sb[tid - off] : 0;
        __syncthreads();
        if (tid < 64) sb[tid] += u;
        __syncthreads();
    }
    if (tid < 64) {
        ofs[tid] = sb[tid] - v;
        int node = (b << 8) + (q << 6) + tid;
        if (node < N_NODES)
            nodeinfo[node] = ((unsigned)v << 23) | (unsigned)(qbase + ofs[tid]);
    }
    if (tid == 63) qtot = sb[63];
    __syncthreads();

    int qt = qtot;
    for (int i = tid; i < qt; i += 256) csr16[qbase + i] = (unsigned short)N_NODES;
    __syncthreads();

    for (int i = tid; i < m; i += 256) {
        int p = binned[ibase + i];
        int dl = (p >> 16) & 255;
        if ((dl >> 6) == q) {
            int r = atomicAdd(&cnt2[dl & 63], 1);
            csr16[qbase + ofs[dl & 63] + r] = (unsigned short)(p & 0xFFFF);
        }
    }
}

// T0/T1 (bf16 feature-half planes) = X(f32) @ W^T; dummy row N_NODES zeroed.
__global__ __launch_bounds__(256) void gemm64_f32(const float* __restrict__ X,
                                                  const float* __restrict__ W,
                                                  unsigned short* __restrict__ T0,
                                                  unsigned short* __restrict__ T1,
                                                  int n_rows) {
    __shared__ float Ws[64 * 64];
    int tid = threadIdx.x;
#pragma unroll
    for (int j = 0; j < 16; ++j) Ws[j * 256 + tid] = W[j * 256 + tid];
    __syncthreads();

    int n = blockIdx.x * 256 + tid;
    if (n >= n_rows) {
        if (n == n_rows) {
            ushort4 z = {0, 0, 0, 0};
            ushort4* t0 = (ushort4*)(T0 + (size_t)n * 32);
            ushort4* t1 = (ushort4*)(T1 + (size_t)n * 32);
#pragma unroll
            for (int k = 0; k < 8; ++k) { t0[k] = z; t1[k] = z; }
        }
        return;
    }

    float4 x[16];
    const float4* xp = (const float4*)(X + (size_t)n * 64);
#pragma unroll
    for (int k = 0; k < 16; ++k) x[k] = xp[k];

    ushort4* t0 = (ushort4*)(T0 + (size_t)n * 32);
    ushort4* t1 = (ushort4*)(T1 + (size_t)n * 32);
    for (int fg = 0; fg < 16; ++fg) {
        float r[4];
#pragma unroll
        for (int fi = 0; fi < 4; ++fi) {
            int f = fg * 4 + fi;
            float acc = 0.f;
#pragma unroll
            for (int k4 = 0; k4 < 16; ++k4) {
                float4 w = *(const float4*)&Ws[f * 64 + k4 * 4];
                float4 xv = x[k4];
                acc += xv.x * w.x + xv.y * w.y + xv.z * w.z + xv.w * w.w;
            }
            r[fi] = acc;
        }
        ushort4 o;
        o.x = f2bf(r[0]); o.y = f2bf(r[1]); o.z = f2bf(r[2]); o.w = f2bf(r[3]);
        if (fg < 8) t0[fg] = o; else t1[fg - 8] = o;
    }
}

// planes = X(bf16 [node][64]) @ W^T; dummy row zeroed.
__global__ __launch_bounds__(256) void gemm64_bf16(const unsigned short* __restrict__ X,
                                                   const float* __restrict__ W,
                                                   unsigned short* __restrict__ T0,
                                                   unsigned short* __restrict__ T1,
                                                   int n_rows) {
    __shared__ float Ws[64 * 64];
    int tid = threadIdx.x;
#pragma unroll
    for (int j = 0; j < 16; ++j) Ws[j * 256 + tid] = W[j * 256 + tid];
    __syncthreads();

    int n = blockIdx.x * 256 + tid;
    if (n >= n_rows) {
        if (n == n_rows) {
            ushort4 z = {0, 0, 0, 0};
            ushort4* t0 = (ushort4*)(T0 + (size_t)n * 32);
            ushort4* t1 = (ushort4*)(T1 + (size_t)n * 32);
#pragma unroll
            for (int k = 0; k < 8; ++k) { t0[k] = z; t1[k] = z; }
        }
        return;
    }

    uint4 xr[8];  // 64 bf16 = 128 B = 8 uint4
    const uint4* xp = (const uint4*)(X + (size_t)n * 64);
#pragma unroll
    for (int k = 0; k < 8; ++k) xr[k] = xp[k];
    float x[64];
    const unsigned* xu = (const unsigned*)xr;
#pragma unroll
    for (int p = 0; p < 32; ++p) {
        unsigned u = xu[p];
        x[2 * p] = bf_lo(u);
        x[2 * p + 1] = bf_hi(u);
    }

    const float4* xv4 = (const float4*)x;
    ushort4* t0 = (ushort4*)(T0 + (size_t)n * 32);
    ushort4* t1 = (ushort4*)(T1 + (size_t)n * 32);
    for (int fg = 0; fg < 16; ++fg) {
        float r[4];
#pragma unroll
        for (int fi = 0; fi < 4; ++fi) {
            int f = fg * 4 + fi;
            float acc = 0.f;
#pragma unroll
            for (int k4 = 0; k4 < 16; ++k4) {
                float4 w = *(const float4*)&Ws[f * 64 + k4 * 4];
                float4 xv = xv4[k4];
                acc += xv.x * w.x + xv.y * w.y + xv.z * w.z + xv.w * w.w;
            }
            r[fi] = acc;
        }
        ushort4 o;
        o.x = f2bf(r[0]); o.y = f2bf(r[1]); o.z = f2bf(r[2]); o.w = f2bf(r[3]);
        if (fg < 8) t0[fg] = o; else t1[fg - 8] = o;
    }
}

// One wave per node, ONE 3.2MB feature-half plane (stays L2-resident).
// 8 lanes/row x uint2(4 bf16) -> 8 rows (512 B) per gather instruction.
// Index/output traffic is nontemporal so it doesn't evict the plane.
// colbase: 0 or 32. mode 0: f32 out. mode 1: tanh + bf16 out.
__global__ __launch_bounds__(256) void aggregate_half(const unsigned short* __restrict__ Tp,
                                                      const unsigned short* __restrict__ csr,
                                                      const unsigned* __restrict__ nodeinfo,
                                                      const float* __restrict__ bias,
                                                      void* __restrict__ outp,
                                                      int colbase, int mode) {
    int node = blockIdx.x * 4 + (threadIdx.x >> 6);
    int lane = threadIdx.x & 63;
    if (node >= N_NODES) return;
    unsigned info = nodeinfo[node];
    int pos = (int)(info & 0x7FFFFFu);
    int groups = (int)(info >> 23) >> 3;
    int q = lane >> 3;   // row within 8-group
    int fl = lane & 7;   // 4-feature slice
    const uv4* ix = (const uv4*)(csr + pos);  // 16B-aligned (pos % 8 == 0)
    const char* Tb = (const char*)Tp;
    int fb = fl * 8;

    float a0 = 0.f, a1 = 0.f, a2 = 0.f, a3 = 0.f;
    if (groups) {
        uv4 iv = __builtin_nontemporal_load(&ix[0]);
        for (int g = 0; g < groups; ++g) {
            uv4 ivn;
            if (g + 1 < groups) ivn = __builtin_nontemporal_load(&ix[g + 1]);
            unsigned w = (q & 2) ? ((q & 4) ? iv.w : iv.y)
                                 : ((q & 4) ? iv.z : iv.x);
            unsigned s = (q & 1) ? (w >> 16) : (w & 0xFFFFu);
            uint2 r = *(const uint2*)(Tb + (size_t)s * 64 + fb);
            a0 += bf_lo(r.x); a1 += bf_hi(r.x);
            a2 += bf_lo(r.y); a3 += bf_hi(r.y);
            iv = ivn;
        }
    }
#pragma unroll
    for (int mask = 8; mask <= 32; mask <<= 1) {
        a0 += __shfl_xor(a0, mask, 64);
        a1 += __shfl_xor(a1, mask, 64);
        a2 += __shfl_xor(a2, mask, 64);
        a3 += __shfl_xor(a3, mask, 64);
    }
    if (q < 4) {
        float a = (q < 2) ? (q == 0 ? a0 : a1) : (q == 2 ? a2 : a3);
        int col = colbase + fl * 4 + q;
        a += bias[col];
        if (mode) {
            float e = __expf(2.f * a);
            a = 1.f - 2.f / (e + 1.f);
            __builtin_nontemporal_store(f2bf(a),
                &((unsigned short*)outp)[(size_t)node * DIM + col]);
        } else {
            __builtin_nontemporal_store(a,
                &((float*)outp)[(size_t)node * DIM + col]);
        }
    }
}

extern "C" void kernel_launch(void* const* d_in, const int* in_sizes, int n_in,
                              void* d_out, int out_size, void* d_ws, size_t ws_size,
                              hipStream_t stream) {
    const float* feat = (const float*)d_in[0];
    const int*   src  = (const int*)d_in[1];
    const int*   dst  = (const int*)d_in[2];
    const float* W1   = (const float*)d_in[3];
    const float* b1   = (const float*)d_in[4];
    const float* W2   = (const float*)d_in[5];
    const float* b2   = (const float*)d_in[6];

    // ws layout (~21.3 MB)
    int*            binned   = (int*)d_ws;                                // 196*12288 ints
    unsigned short* csr16    = (unsigned short*)(binned + NBK * CSR_CAP); // 784*3072 ushort
    unsigned*       nodeinfo = (unsigned*)(csr16 + NBK * 4 * QCAP);       // 50000
    int*            bcur     = (int*)(nodeinfo + N_NODES);                // 196*16
    unsigned short* t        = (unsigned short*)(bcur + NBK * 16 + 8);    // 2 planes
    unsigned short* T0 = t;
    unsigned short* T1 = t + PLANE;

    unsigned short* h = (unsigned short*)d_out;  // bf16 h staged in d_out
    float* out = (float*)d_out;

    const int NB = (N_NODES + 3) / 4;
    const int GB = (N_NODES + 256) / 256;  // covers dummy zero row N_NODES

    // ---- CSR build (once; reused by both layers) ----
    init_bcur<<<1, 256, 0, stream>>>(bcur);
    bin_edges<<<BIN_BLOCKS, 256, 0, stream>>>(src, dst, bcur, binned);
    build_csr<<<NBK * 4, 256, 0, stream>>>(binned, bcur, nodeinfo, csr16);

    // ---- Layer 1: h = tanh(scatter(feat @ W1^T) + b1), bf16 -> d_out ----
    gemm64_f32<<<GB, 256, 0, stream>>>(feat, W1, T0, T1, N_NODES);
    aggregate_half<<<NB, 256, 0, stream>>>(T0, csr16, nodeinfo, b1, h, 0, 1);
    aggregate_half<<<NB, 256, 0, stream>>>(T1, csr16, nodeinfo, b1, h, 32, 1);

    // ---- Layer 2: out = scatter(h @ W2^T) + b2, f32 ----
    gemm64_bf16<<<GB, 256, 0, stream>>>(h, W2, T0, T1, N_NODES);
    aggregate_half<<<NB, 256, 0, stream>>>(T0, csr16, nodeinfo, b2, out, 0, 0);
    aggregate_half<<<NB, 256, 0, stream>>>(T1, csr16, nodeinfo, b2, out, 32, 0);
}

// Round 11
// 243.876 us; speedup vs baseline: 1.2857x; 1.2857x over previous
//
#include <hip/hip_runtime.h>

#define N_NODES 50000
#define N_EDGES 1600000
#define DIM 64
#define NBK 196          // buckets of 256 dst-nodes
#define BIN_BLOCKS 391   // ceil(1.6M / 4096)
#define CSR_CAP 12288    // per-bucket slots
#define QCAP 3072        // per-quarter slots (padded mean ~2530, ~9-sigma margin)
#define GEMM_BLOCKS 197  // covers 50000 rows + dummy zero row

// f32 -> bf16 round-to-nearest-even
__device__ __forceinline__ unsigned short f2bf(float f) {
    union { float f; unsigned u; } v; v.f = f;
    unsigned r = v.u + 0x7FFF + ((v.u >> 16) & 1);
    return (unsigned short)(r >> 16);
}
__device__ __forceinline__ float bf_lo(unsigned u) {
    union { unsigned u; float f; } v; v.u = u << 16;  return v.f;
}
__device__ __forceinline__ float bf_hi(unsigned u) {
    union { unsigned u; float f; } v; v.u = u & 0xFFFF0000u;  return v.f;
}
__device__ __forceinline__ float bf2f(unsigned short h) {
    union { unsigned u; float f; } v; v.u = ((unsigned)h) << 16;  return v.f;
}

// Fused: blocks [0, BIN_BLOCKS) partition edges into per-bucket regions
// (R6-proven binning; bcur is ZERO-BASED per-bucket count, memset before);
// blocks [BIN_BLOCKS, BIN_BLOCKS+GEMM_BLOCKS) compute T = feat @ W1^T (bf16)
// with dummy row N_NODES zeroed. The two halves touch disjoint data.
__global__ __launch_bounds__(256) void bin_and_gemm1(const int* __restrict__ src,
                                                     const int* __restrict__ dst,
                                                     int* __restrict__ bcur,
                                                     int* __restrict__ binned,
                                                     const float* __restrict__ X,
                                                     const float* __restrict__ W,
                                                     unsigned short* __restrict__ T) {
    __shared__ int cnt[NBK];
    __shared__ int lofs[NBK];
    __shared__ int shiftv[NBK];
    __shared__ int sb[256];
    __shared__ int stag[4096];
    __shared__ unsigned char stb[4096];
    __shared__ float Ws[64 * 64];
    int tid = threadIdx.x;

    if (blockIdx.x >= BIN_BLOCKS) {
        // ---------------- GEMM path (feat f32 -> T bf16) ----------------
#pragma unroll
        for (int j = 0; j < 16; ++j) Ws[j * 256 + tid] = W[j * 256 + tid];
        __syncthreads();

        int n = (blockIdx.x - BIN_BLOCKS) * 256 + tid;
        if (n > N_NODES) return;
        ushort4* tp = (ushort4*)(T + (size_t)n * 64);
        if (n == N_NODES) {  // dummy zero row (pad target)
            ushort4 z = {0, 0, 0, 0};
#pragma unroll
            for (int k = 0; k < 16; ++k) tp[k] = z;
            return;
        }

        float4 x[16];
        const float4* xp = (const float4*)(X + (size_t)n * 64);
#pragma unroll
        for (int k = 0; k < 16; ++k) x[k] = xp[k];

        for (int fg = 0; fg < 16; ++fg) {
            float r[4];
#pragma unroll
            for (int fi = 0; fi < 4; ++fi) {
                int f = fg * 4 + fi;
                float acc = 0.f;
#pragma unroll
                for (int k4 = 0; k4 < 16; ++k4) {
                    float4 w = *(const float4*)&Ws[f * 64 + k4 * 4];
                    float4 xv = x[k4];
                    acc += xv.x * w.x + xv.y * w.y + xv.z * w.z + xv.w * w.w;
                }
                r[fi] = acc;
            }
            ushort4 o;
            o.x = f2bf(r[0]); o.y = f2bf(r[1]); o.z = f2bf(r[2]); o.w = f2bf(r[3]);
            tp[fg] = o;
        }
        return;
    }

    // ---------------- Binning path (R6-proven) ----------------
    if (tid < NBK) cnt[tid] = 0;
    __syncthreads();

    int base = blockIdx.x * 4096;
    int nedge = N_EDGES - base;
    if (nedge > 4096) nedge = 4096;

    int myb[16], myr[16], myp[16];
#pragma unroll
    for (int i = 0; i < 16; ++i) {
        int e = base + i * 256 + tid;
        myb[i] = -1;
        if (e < N_EDGES) {
            int s = src[e], d = dst[e];
            int b = d >> 8;
            myb[i] = b;
            myp[i] = ((d & 255) << 16) | s;
            myr[i] = atomicAdd(&cnt[b], 1);
        }
    }
    __syncthreads();

    int c = (tid < NBK) ? cnt[tid] : 0;
    sb[tid] = c;
    __syncthreads();
    for (int off = 1; off < 256; off <<= 1) {
        int u = (tid >= off) ? sb[tid - off] : 0;
        __syncthreads();
        sb[tid] += u;
        __syncthreads();
    }
    if (tid < NBK) {
        lofs[tid] = sb[tid] - c;
        if (c) shiftv[tid] = tid * CSR_CAP + atomicAdd(&bcur[tid * 16], c) - lofs[tid];
    }
    __syncthreads();

#pragma unroll
    for (int i = 0; i < 16; ++i) {
        if (myb[i] >= 0) {
            int idx = lofs[myb[i]] + myr[i];
            stag[idx] = myp[i];
            stb[idx] = (unsigned char)myb[i];
        }
    }
    __syncthreads();

    for (int i = tid; i < nedge; i += 256)
        binned[i + shiftv[stb[i]]] = stag[i];
}

// One workgroup per (bucket, dst-quarter). Counts padded to MULT-16 with dummy
// src = N_NODES (zero row). nodeinfo = (padded_cnt << 23) | pos, pos%16==0.
__global__ __launch_bounds__(256) void build_csr(const int* __restrict__ binned,
                                                 const int* __restrict__ bcur,
                                                 unsigned* __restrict__ nodeinfo,
                                                 unsigned short* __restrict__ csr16) {
    __shared__ int cnt[64], cnt2[64], ofs[64], sb[64];
    __shared__ int qtot;
    int tid = threadIdx.x;
    int b = blockIdx.x >> 2;
    int q = blockIdx.x & 3;
    int ibase = b * CSR_CAP;
    int qbase = (b * 4 + q) * QCAP;
    int m = bcur[b * 16];          // zero-based count
    if (m > CSR_CAP) m = CSR_CAP;
    if (tid < 64) { cnt[tid] = 0; cnt2[tid] = 0; }
    __syncthreads();

    for (int i = tid; i < m; i += 256) {
        int dl = (binned[ibase + i] >> 16) & 255;
        if ((dl >> 6) == q) atomicAdd(&cnt[dl & 63], 1);
    }
    __syncthreads();

    int v = 0;
    if (tid < 64) { v = (cnt[tid] + 15) & ~15; sb[tid] = v; }  // mult-16 pad
    __syncthreads();
    for (int off = 1; off < 64; off <<= 1) {
        int u = (tid >= off && tid < 64) ? sb[tid - off] : 0;
        __syncthreads();
        if (tid < 64) sb[tid] += u;
        __syncthreads();
    }
    if (tid < 64) {
        ofs[tid] = sb[tid] - v;
        int node = (b << 8) + (q << 6) + tid;
        if (node < N_NODES)
            nodeinfo[node] = ((unsigned)v << 23) | (unsigned)(qbase + ofs[tid]);
    }
    if (tid == 63) qtot = sb[63];
    __syncthreads();

    int qt = qtot;
    for (int i = tid; i < qt; i += 256) csr16[qbase + i] = (unsigned short)N_NODES;
    __syncthreads();

    for (int i = tid; i < m; i += 256) {
        int p = binned[ibase + i];
        int dl = (p >> 16) & 255;
        if ((dl >> 6) == q) {
            int r = atomicAdd(&cnt2[dl & 63], 1);
            csr16[qbase + ofs[dl & 63] + r] = (unsigned short)(p & 0xFFFF);
        }
    }
}

// T(bf16) = X(bf16) @ W^T; dummy row zeroed. (layer 2)
__global__ __launch_bounds__(256) void gemm64_bf16(const unsigned short* __restrict__ X,
                                                   const float* __restrict__ W,
                                                   unsigned short* __restrict__ T,
                                                   int n_rows) {
    __shared__ float Ws[64 * 64];
    int tid = threadIdx.x;
#pragma unroll
    for (int j = 0; j < 16; ++j) Ws[j * 256 + tid] = W[j * 256 + tid];
    __syncthreads();

    int n = blockIdx.x * 256 + tid;
    if (n >= n_rows) {
        if (n == n_rows) {
            ushort4 z = {0, 0, 0, 0};
            ushort4* tp = (ushort4*)(T + (size_t)n * 64);
#pragma unroll
            for (int k = 0; k < 16; ++k) tp[k] = z;
        }
        return;
    }

    uint4 xr[8];  // 64 bf16 = 128 B = 8 uint4
    const uint4* xp = (const uint4*)(X + (size_t)n * 64);
#pragma unroll
    for (int k = 0; k < 8; ++k) xr[k] = xp[k];
    float x[64];
    const unsigned* xu = (const unsigned*)xr;
#pragma unroll
    for (int p = 0; p < 32; ++p) {
        unsigned u = xu[p];
        x[2 * p] = bf_lo(u);
        x[2 * p + 1] = bf_hi(u);
    }

    const float4* xv4 = (const float4*)x;
    ushort4* tp = (ushort4*)(T + (size_t)n * 64);
    for (int fg = 0; fg < 16; ++fg) {
        float r[4];
#pragma unroll
        for (int fi = 0; fi < 4; ++fi) {
            int f = fg * 4 + fi;
            float acc = 0.f;
#pragma unroll
            for (int k4 = 0; k4 < 16; ++k4) {
                float4 w = *(const float4*)&Ws[f * 64 + k4 * 4];
                float4 xv = xv4[k4];
                acc += xv.x * w.x + xv.y * w.y + xv.z * w.z + xv.w * w.w;
            }
            r[fi] = acc;
        }
        ushort4 o;
        o.x = f2bf(r[0]); o.y = f2bf(r[1]); o.z = f2bf(r[2]); o.w = f2bf(r[3]);
        tp[fg] = o;
    }
}

// One 64-lane wave per node, lane = feature. Counts are mult-16: each
// iteration loads 2 index uint4s and issues 16 independent 128B row gathers
// (2x the in-flight bytes of R6's unroll-8). No tail, no branches in loop.
__global__ __launch_bounds__(256) void aggregate(const unsigned short* __restrict__ T,
                                                 const unsigned short* __restrict__ csr,
                                                 const unsigned* __restrict__ nodeinfo,
                                                 const float* __restrict__ bias,
                                                 void* __restrict__ outp,
                                                 int mode) {
    int node = blockIdx.x * 4 + (threadIdx.x >> 6);
    int lane = threadIdx.x & 63;
    if (node >= N_NODES) return;
    unsigned info = nodeinfo[node];
    int pos = (int)(info & 0x7FFFFFu);
    int groups = (int)(info >> 23) >> 3;   // even (pcnt mult 16)
    const uint4* ix = (const uint4*)(csr + pos);  // 32B-aligned
    float acc = bias[lane];
    float acc2 = 0.f;
    for (int g = 0; g < groups; g += 2) {
        uint4 ia = ix[g];
        uint4 ib = ix[g + 1];
        int s0 = ia.x & 0xFFFF, s1 = ia.x >> 16;
        int s2 = ia.y & 0xFFFF, s3 = ia.y >> 16;
        int s4 = ia.z & 0xFFFF, s5 = ia.z >> 16;
        int s6 = ia.w & 0xFFFF, s7 = ia.w >> 16;
        int u0 = ib.x & 0xFFFF, u1 = ib.x >> 16;
        int u2 = ib.y & 0xFFFF, u3 = ib.y >> 16;
        int u4 = ib.z & 0xFFFF, u5 = ib.z >> 16;
        int u6 = ib.w & 0xFFFF, u7 = ib.w >> 16;
        unsigned short v0 = T[(size_t)s0 * DIM + lane];
        unsigned short v1 = T[(size_t)s1 * DIM + lane];
        unsigned short v2 = T[(size_t)s2 * DIM + lane];
        unsigned short v3 = T[(size_t)s3 * DIM + lane];
        unsigned short v4 = T[(size_t)s4 * DIM + lane];
        unsigned short v5 = T[(size_t)s5 * DIM + lane];
        unsigned short v6 = T[(size_t)s6 * DIM + lane];
        unsigned short v7 = T[(size_t)s7 * DIM + lane];
        unsigned short w0 = T[(size_t)u0 * DIM + lane];
        unsigned short w1 = T[(size_t)u1 * DIM + lane];
        unsigned short w2 = T[(size_t)u2 * DIM + lane];
        unsigned short w3 = T[(size_t)u3 * DIM + lane];
        unsigned short w4 = T[(size_t)u4 * DIM + lane];
        unsigned short w5 = T[(size_t)u5 * DIM + lane];
        unsigned short w6 = T[(size_t)u6 * DIM + lane];
        unsigned short w7 = T[(size_t)u7 * DIM + lane];
        acc  += (bf2f(v0) + bf2f(v1)) + (bf2f(v2) + bf2f(v3)) +
                (bf2f(v4) + bf2f(v5)) + (bf2f(v6) + bf2f(v7));
        acc2 += (bf2f(w0) + bf2f(w1)) + (bf2f(w2) + bf2f(w3)) +
                (bf2f(w4) + bf2f(w5)) + (bf2f(w6) + bf2f(w7));
    }
    acc += acc2;
    if (mode) {
        float e = __expf(2.f * acc);
        acc = 1.f - 2.f / (e + 1.f);
        ((unsigned short*)outp)[(size_t)node * DIM + lane] = f2bf(acc);
    } else {
        ((float*)outp)[(size_t)node * DIM + lane] = acc;
    }
}

extern "C" void kernel_launch(void* const* d_in, const int* in_sizes, int n_in,
                              void* d_out, int out_size, void* d_ws, size_t ws_size,
                              hipStream_t stream) {
    const float* feat = (const float*)d_in[0];
    const int*   src  = (const int*)d_in[1];
    const int*   dst  = (const int*)d_in[2];
    const float* W1   = (const float*)d_in[3];
    const float* b1   = (const float*)d_in[4];
    const float* W2   = (const float*)d_in[5];
    const float* b2   = (const float*)d_in[6];

    // ws layout (~21.3 MB)
    int*            binned   = (int*)d_ws;                                // 196*12288 ints
    unsigned short* csr16    = (unsigned short*)(binned + NBK * CSR_CAP); // 784*3072 ushort
    unsigned*       nodeinfo = (unsigned*)(csr16 + NBK * 4 * QCAP);       // 50000
    int*            bcur     = (int*)(nodeinfo + N_NODES);                // 196*16
    unsigned short* t        = (unsigned short*)(bcur + NBK * 16 + 8);    // 50001*64 bf16

    unsigned short* h = (unsigned short*)d_out;  // bf16 h staged in d_out
    float* out = (float*)d_out;

    const int NB = (N_NODES + 3) / 4;

    // ---- CSR build + layer-1 transform (overlapped) ----
    hipMemsetAsync(bcur, 0, NBK * 16 * sizeof(int), stream);
    bin_and_gemm1<<<BIN_BLOCKS + GEMM_BLOCKS, 256, 0, stream>>>(
        src, dst, bcur, binned, feat, W1, t);
    build_csr<<<NBK * 4, 256, 0, stream>>>(binned, bcur, nodeinfo, csr16);

    // ---- Layer 1 aggregate: h = tanh(agg + b1), bf16 -> d_out ----
    aggregate<<<NB, 256, 0, stream>>>(t, csr16, nodeinfo, b1, h, 1);

    // ---- Layer 2: out = agg(h @ W2^T) + b2, f32 ----
    gemm64_bf16<<<GEMM_BLOCKS, 256, 0, stream>>>(h, W2, t, N_NODES);
    aggregate<<<NB, 256, 0, stream>>>(t, csr16, nodeinfo, b2, out, 0);
}